// Round 1
// baseline (1172.080 us; speedup 1.0000x reference)
//
#include <hip/hip_runtime.h>
#include <stdint.h>

#define TT 8
#define NN 40000
#define FF 256
#define EE 640000
#define BB 1024
#define ROWS 320000   // TT*NN

typedef __attribute__((ext_vector_type(8))) short s16x8;
typedef __attribute__((ext_vector_type(4))) float f32x4;

__device__ __forceinline__ unsigned short f2bf(float f){
  unsigned int u = __float_as_uint(f);
  u += 0x7fffu + ((u >> 16) & 1u);
  return (unsigned short)(u >> 16);
}
__device__ __forceinline__ float bflo(unsigned int u){ return __uint_as_float(u << 16); }
__device__ __forceinline__ float bfhi(unsigned int u){ return __uint_as_float(u & 0xffff0000u); }

// global -> LDS direct DMA, 16B per lane. LDS dest must be wave-uniform base + lane*16.
__device__ __forceinline__ void gl2lds16(const void* g, void* l){
  auto gp = reinterpret_cast<const unsigned int __attribute__((address_space(1)))*>(
      reinterpret_cast<uintptr_t>(g));
  auto lp = reinterpret_cast<unsigned int __attribute__((address_space(3)))*>(
      static_cast<unsigned int>(reinterpret_cast<uintptr_t>(l)));
  __builtin_amdgcn_global_load_lds(gp, lp, 16, 0, 0);
}

// ---------------- weight prep: transpose/convert to bf16 ----------------
__global__ void prep_k(const float* __restrict__ proj_w, const float* __restrict__ w1,
                       const float* __restrict__ w2, const float* __restrict__ wih,
                       const float* __restrict__ whh,
                       unsigned short* __restrict__ projwt, unsigned short* __restrict__ w1t,
                       unsigned short* __restrict__ w2t, unsigned short* __restrict__ wihb,
                       uint2* __restrict__ whhp)
{
  int i = blockIdx.x * 256 + threadIdx.x;
  if (i < 32768) {                      // projwt[p][f] = proj_w[f][p]
    int p = i >> 8, f = i & 255;
    projwt[i] = f2bf(proj_w[f * 128 + p]);
  } else if (i < 49152) {               // w1t[o][c] = w1[c][o]
    int k = i - 32768; int o = k >> 7, c = k & 127;
    w1t[k] = f2bf(w1[c * 128 + o]);
  } else if (i < 65536) {
    int k = i - 49152; int o = k >> 7, c = k & 127;
    w2t[k] = f2bf(w2[c * 128 + o]);
  } else if (i < 163840) {              // wihb = w_ih as-is (rows are output cols)
    int k = i - 65536;
    wihb[k] = f2bf(wih[k]);
  } else if (i < 180224) {              // whhp[k][j] = {whh[j][k], whh[128+j][k], whh[256+j][k], 0}
    int k = i - 163840; int kk = k >> 7, j = k & 127;
    unsigned int lo = (unsigned int)f2bf(whh[j * 128 + kk]) |
                      ((unsigned int)f2bf(whh[(128 + j) * 128 + kk]) << 16);
    unsigned int hi = (unsigned int)f2bf(whh[(256 + j) * 128 + kk]);
    whhp[k] = make_uint2(lo, hi);
  }
}

// ---------------- CSR build ----------------
__global__ void init_k(int* __restrict__ counts, int* __restrict__ fill){
  int i = blockIdx.x * 256 + threadIdx.x;
  if (i < NN) { counts[i] = 0; fill[i] = 0; }
}
__global__ void count_k(const int* __restrict__ dst, int* __restrict__ counts){
  int i = blockIdx.x * 256 + threadIdx.x;
  if (i < EE) atomicAdd(&counts[dst[i]], 1);
}
__global__ void scan_k(const int* __restrict__ counts, int* __restrict__ rp,
                       float* __restrict__ dinv)
{
  __shared__ int sums[1024];
  const int CH = 40;
  int t = threadIdx.x;
  int beg = t * CH, end = beg + CH; if (end > NN) end = NN; if (beg > NN) beg = NN;
  int s = 0;
  for (int i = beg; i < end; i++) s += counts[i];
  sums[t] = s;
  __syncthreads();
  for (int off = 1; off < 1024; off <<= 1) {
    int add = (t >= off) ? sums[t - off] : 0;
    __syncthreads();
    sums[t] += add;
    __syncthreads();
  }
  int run = sums[t] - s;   // exclusive prefix for this chunk
  for (int i = beg; i < end; i++) { rp[i] = run; run += counts[i]; }
  if (t == 1023) rp[NN] = sums[1023];
  for (int i = beg; i < end; i++) dinv[i] = rsqrtf((float)(counts[i] + 1));
}
__global__ void fill_k(const int* __restrict__ src, const int* __restrict__ dst,
                       const int* __restrict__ rp, int* __restrict__ fill,
                       int* __restrict__ ci)
{
  int i = blockIdx.x * 256 + threadIdx.x;
  if (i < EE) {
    int d = dst[i];
    int pos = rp[d] + atomicAdd(&fill[d], 1);
    ci[pos] = src[i];
  }
}

// ---------------- tiled MFMA GEMM: C[r][c] = sum_k A[r][k]*Bt[c][k] ----------------
// A is bf16 (global_load_lds).
// MODE 1: bf16 out = acc*dinv[row%NN];  MODE 2: f32 out = acc.
template<int MODE>
__global__ __launch_bounds__(256)
void gemm_k(const void* __restrict__ Ap, const short* __restrict__ Bt,
            void* __restrict__ Cp, int K, int ldc,
            const float* __restrict__ dinv)
{
  __shared__ short lA[128 * 64];
  __shared__ short lB[128 * 64];
  const int tid = threadIdx.x;
  const int lane = tid & 63, wave = tid >> 6;
  const int row0 = blockIdx.x * 128;
  const int col0 = blockIdx.y * 128;
  const int qr = (wave & 1) * 64, qc = (wave >> 1) * 64;
  const int m = lane & 15, q = lane >> 4;

  f32x4 acc[4][4];
#pragma unroll
  for (int i = 0; i < 4; i++)
#pragma unroll
    for (int j = 0; j < 4; j++) acc[i][j] = (f32x4){0.f, 0.f, 0.f, 0.f};

  for (int k0 = 0; k0 < K; k0 += 64) {
    __syncthreads();
    {
      const short* A = (const short*)Ap;
#pragma unroll
      for (int i = 0; i < 4; i++) {
        int c = wave * 4 + i;
        int row = c * 8 + (lane >> 3);
        int kg = (lane & 7) ^ (row & 7);
        gl2lds16(A + (size_t)(row0 + row) * K + k0 + kg * 8, lA + c * 512);
      }
    }
#pragma unroll
    for (int i = 0; i < 4; i++) {
      int c = wave * 4 + i;
      int row = c * 8 + (lane >> 3);
      int kg = (lane & 7) ^ (row & 7);
      gl2lds16(Bt + (size_t)(col0 + row) * K + k0 + kg * 8, lB + c * 512);
    }
    __syncthreads();
#pragma unroll
    for (int ks = 0; ks < 2; ks++) {
      s16x8 af[4], bf[4];
#pragma unroll
      for (int i = 0; i < 4; i++) {
        int R = qr + 16 * i + m;
        af[i] = *(const s16x8*)&lA[R * 64 + (((ks * 4 + q) ^ (R & 7)) * 8)];
        int RB = qc + 16 * i + m;
        bf[i] = *(const s16x8*)&lB[RB * 64 + (((ks * 4 + q) ^ (RB & 7)) * 8)];
      }
#pragma unroll
      for (int i = 0; i < 4; i++)
#pragma unroll
        for (int j = 0; j < 4; j++)
          acc[i][j] = __builtin_amdgcn_mfma_f32_16x16x32_bf16(af[i], bf[j], acc[i][j], 0, 0, 0);
    }
  }
#pragma unroll
  for (int i = 0; i < 4; i++) {
    int rbase = row0 + qr + 16 * i + q * 4;
#pragma unroll
    for (int j = 0; j < 4; j++) {
      int col = col0 + qc + 16 * j + m;
#pragma unroll
      for (int rr = 0; rr < 4; rr++) {
        int rg = rbase + rr;
        float v = acc[i][j][rr];
        if (MODE == 1) {
          v *= dinv[rg % NN];
          ((unsigned short*)Cp)[(size_t)rg * ldc + col] = f2bf(v);
        } else {
          ((float*)Cp)[(size_t)rg * ldc + col] = v;
        }
      }
    }
  }
}

// ---------------- fused proj + gcn1 matmul ----------------
// Per 128-row block: Hp = relu(x@Wp + b) kept in LDS (bf16, swizzled), then
// Ms1 = dinv[row] * (Hp @ W1) written directly. Saves the 164 MB Hp HBM
// round-trip and one kernel launch.
// LDS: 48 KB (S0=x/W1 staging 16K, lH=Hp 32K overlapping old lB region) -> 3 blk/CU.
__global__ __launch_bounds__(256)
void projgcn_k(const float* __restrict__ x, const short* __restrict__ projwt,
               const short* __restrict__ w1t, const float* __restrict__ proj_b,
               const float* __restrict__ dinv, unsigned short* __restrict__ Ms1)
{
  __shared__ short lds[128 * 64 * 3];   // 48 KB
  short* lA = lds;                      // 16 KB: x tile (matmul1) / W1 tile (matmul2)
  short* lB = lds + 8192;               // 16 KB: projwt tile (matmul1)
  short* lH = lds + 8192;               // 32 KB: Hp (overwrites lB after matmul1)
  const int tid = threadIdx.x;
  const int lane = tid & 63, wave = tid >> 6;
  const int row0 = blockIdx.x * 128;
  const int qr = (wave & 1) * 64, qc = (wave >> 1) * 64;
  const int m = lane & 15, q = lane >> 4;

  f32x4 acc[4][4];
#pragma unroll
  for (int i = 0; i < 4; i++)
#pragma unroll
    for (int j = 0; j < 4; j++) acc[i][j] = (f32x4){0.f, 0.f, 0.f, 0.f};

  // ---- matmul 1: Hp = x(128x256) @ projwt^T ----
  for (int k0 = 0; k0 < 256; k0 += 64) {
    __syncthreads();
    {   // stage A: fp32 -> bf16
      int row = tid >> 1, half = tid & 1;
      const float* gp = x + (size_t)(row0 + row) * 256 + k0 + half * 32;
#pragma unroll
      for (int gi = 0; gi < 4; gi++) {
        float4 v0 = *(const float4*)(gp + gi * 8);
        float4 v1 = *(const float4*)(gp + gi * 8 + 4);
        uint4 w;
        w.x = (unsigned)f2bf(v0.x) | ((unsigned)f2bf(v0.y) << 16);
        w.y = (unsigned)f2bf(v0.z) | ((unsigned)f2bf(v0.w) << 16);
        w.z = (unsigned)f2bf(v1.x) | ((unsigned)f2bf(v1.y) << 16);
        w.w = (unsigned)f2bf(v1.z) | ((unsigned)f2bf(v1.w) << 16);
        int g = half * 4 + gi;
        *(uint4*)&lA[row * 64 + ((g ^ (row & 7)) * 8)] = w;
      }
    }
#pragma unroll
    for (int i = 0; i < 4; i++) {   // stage B: projwt (K=256)
      int c = wave * 4 + i;
      int row = c * 8 + (lane >> 3);
      int kg = (lane & 7) ^ (row & 7);
      gl2lds16(projwt + (size_t)row * 256 + k0 + kg * 8, lB + c * 512);
    }
    __syncthreads();
#pragma unroll
    for (int ks = 0; ks < 2; ks++) {
      s16x8 af[4], bf[4];
#pragma unroll
      for (int i = 0; i < 4; i++) {
        int R = qr + 16 * i + m;
        af[i] = *(const s16x8*)&lA[R * 64 + (((ks * 4 + q) ^ (R & 7)) * 8)];
        int RB = qc + 16 * i + m;
        bf[i] = *(const s16x8*)&lB[RB * 64 + (((ks * 4 + q) ^ (RB & 7)) * 8)];
      }
#pragma unroll
      for (int i = 0; i < 4; i++)
#pragma unroll
        for (int j = 0; j < 4; j++)
          acc[i][j] = __builtin_amdgcn_mfma_f32_16x16x32_bf16(af[i], bf[j], acc[i][j], 0, 0, 0);
    }
  }
  __syncthreads();   // everyone done reading lA/lB before lH overwrites lB

  // ---- epilogue 1: relu(acc + b) -> lH (bf16, swizzled like an A-tile, k = col) ----
#pragma unroll
  for (int i = 0; i < 4; i++) {
    int rb = qr + 16 * i + q * 4;
#pragma unroll
    for (int j = 0; j < 4; j++) {
      int c = qc + 16 * j + m;
      int chalf = c & 64;
      int gsw = (c >> 3) & 7;
      float bv = proj_b[c];
#pragma unroll
      for (int rr = 0; rr < 4; rr++) {
        int r_loc = rb + rr;
        float v = fmaxf(acc[i][j][rr] + bv, 0.f);
        lH[r_loc * 128 + chalf + ((gsw ^ (r_loc & 7)) << 3) + (c & 7)] = (short)f2bf(v);
      }
      acc[i][j] = (f32x4){0.f, 0.f, 0.f, 0.f};
    }
  }

  // ---- matmul 2: Ms1 = Hp(128x128) @ w1t^T ----
  for (int k0 = 0; k0 < 128; k0 += 64) {
    __syncthreads();   // k0=0: lH writes done; k0=64: lA reads of prev tile done
#pragma unroll
    for (int i = 0; i < 4; i++) {   // stage W1 tile into lA (K=128)
      int c = wave * 4 + i;
      int row = c * 8 + (lane >> 3);
      int kg = (lane & 7) ^ (row & 7);
      gl2lds16(w1t + (size_t)row * 128 + k0 + kg * 8, lA + c * 512);
    }
    __syncthreads();
#pragma unroll
    for (int ks = 0; ks < 2; ks++) {
      s16x8 af[4], bf[4];
#pragma unroll
      for (int i = 0; i < 4; i++) {
        int R = qr + 16 * i + m;
        af[i] = *(const s16x8*)&lH[R * 128 + k0 + (((ks * 4 + q) ^ (R & 7)) << 3)];
        int RB = qc + 16 * i + m;
        bf[i] = *(const s16x8*)&lA[RB * 64 + (((ks * 4 + q) ^ (RB & 7)) << 3)];
      }
#pragma unroll
      for (int i = 0; i < 4; i++)
#pragma unroll
        for (int j = 0; j < 4; j++)
          acc[i][j] = __builtin_amdgcn_mfma_f32_16x16x32_bf16(af[i], bf[j], acc[i][j], 0, 0, 0);
    }
  }

  // ---- epilogue 2: Ms1 = dinv[node] * acc ----
#pragma unroll
  for (int i = 0; i < 4; i++) {
    int rbase = row0 + qr + 16 * i + q * 4;
#pragma unroll
    for (int j = 0; j < 4; j++) {
      int col = qc + 16 * j + m;
#pragma unroll
      for (int rr = 0; rr < 4; rr++) {
        int rg = rbase + rr;
        float v = acc[i][j][rr] * dinv[rg % NN];
        Ms1[(size_t)rg * 128 + col] = f2bf(v);
      }
    }
  }
}

// ---------------- GCN aggregation: one wave per (t,node) -------------------
// uint2 loads: each half-wave (32 lanes x 8 B) covers one full 256 B row ->
// 2 edges per load instruction, 8-deep unroll = 8 rows in flight (2x the MLP
// of the previous version at half the issue count). Cross-half combine via
// one shfl_xor(32) at the end. Blocks dispatched t-major => ~one 10 MB slab
// hot at a time (LLC-resident gathers).
__global__ __launch_bounds__(256)
void agg_k(const uint2* __restrict__ Ms, uint2* __restrict__ Hout,
           const int* __restrict__ rp, const int* __restrict__ ci,
           const float* __restrict__ dinv, const float* __restrict__ bias)
{
  int widx = blockIdx.x * 4 + (threadIdx.x >> 6);
  int lane = threadIdx.x & 63;
  int li = lane & 31, h = lane >> 5;
  int t = widx / NN;
  int v = widx - t * NN;
  const uint2* base = Ms + (size_t)t * NN * 32 + li;

  uint2 su = base[(size_t)v * 32];        // self-loop term (both halves read same line)
  float a0, a1, a2, a3;
  if (h == 0) { a0 = bflo(su.x); a1 = bfhi(su.x); a2 = bflo(su.y); a3 = bfhi(su.y); }
  else        { a0 = 0.f; a1 = 0.f; a2 = 0.f; a3 = 0.f; }

  int e0 = rp[v], e1 = rp[v + 1];
  for (int chunk = e0; chunk < e1; chunk += 64) {
    int cnt = min(64, e1 - chunk);
    int myIdx = (lane < cnt) ? ci[chunk + lane] : 0;
    int j = 0;
    for (; j + 8 <= cnt; j += 8) {
      int s0 = __shfl(myIdx, j + h, 64);
      int s1 = __shfl(myIdx, j + 2 + h, 64);
      int s2 = __shfl(myIdx, j + 4 + h, 64);
      int s3 = __shfl(myIdx, j + 6 + h, 64);
      uint2 w0 = base[(size_t)s0 * 32];
      uint2 w1 = base[(size_t)s1 * 32];
      uint2 w2 = base[(size_t)s2 * 32];
      uint2 w3 = base[(size_t)s3 * 32];
      a0 += bflo(w0.x) + bflo(w1.x) + bflo(w2.x) + bflo(w3.x);
      a1 += bfhi(w0.x) + bfhi(w1.x) + bfhi(w2.x) + bfhi(w3.x);
      a2 += bflo(w0.y) + bflo(w1.y) + bflo(w2.y) + bflo(w3.y);
      a3 += bfhi(w0.y) + bfhi(w1.y) + bfhi(w2.y) + bfhi(w3.y);
    }
    for (; j + 2 <= cnt; j += 2) {
      int s = __shfl(myIdx, j + h, 64);
      uint2 w = base[(size_t)s * 32];
      a0 += bflo(w.x); a1 += bfhi(w.x); a2 += bflo(w.y); a3 += bfhi(w.y);
    }
    if (j < cnt) {
      int s = __shfl(myIdx, j, 64);     // shfl by all lanes (source may be in either half)
      if (h == 0) {
        uint2 w = base[(size_t)s * 32];
        a0 += bflo(w.x); a1 += bfhi(w.x); a2 += bflo(w.y); a3 += bfhi(w.y);
      }
    }
  }
  a0 += __shfl_xor(a0, 32, 64);
  a1 += __shfl_xor(a1, 32, 64);
  a2 += __shfl_xor(a2, 32, 64);
  a3 += __shfl_xor(a3, 32, 64);
  if (h == 0) {
    float dv = dinv[v];
    float r0 = fmaxf(fmaf(dv, a0, bias[li * 4 + 0]), 0.f);
    float r1 = fmaxf(fmaf(dv, a1, bias[li * 4 + 1]), 0.f);
    float r2 = fmaxf(fmaf(dv, a2, bias[li * 4 + 2]), 0.f);
    float r3 = fmaxf(fmaf(dv, a3, bias[li * 4 + 3]), 0.f);
    uint2 o;
    o.x = (unsigned)f2bf(r0) | ((unsigned)f2bf(r1) << 16);
    o.y = (unsigned)f2bf(r2) | ((unsigned)f2bf(r3) << 16);
    Hout[(size_t)widx * 32 + li] = o;
  }
}

// ---------------- gather target embeddings -> TGT (bf16, [t][b][256]) ----------------
__global__ void gather_k(const unsigned int* __restrict__ h1, const unsigned int* __restrict__ h2,
                         const int* __restrict__ tix, unsigned int* __restrict__ TGT)
{
  int i = blockIdx.x * 256 + threadIdx.x;   // over 8*1024*128 dwords
  int dw = i & 127; int r = i >> 7; int b = r & 1023; int t = r >> 10;
  int node = tix[b];
  size_t src = ((size_t)t * NN + node) * 64 + (dw & 63);
  unsigned int val = (dw < 64) ? h1[src] : h2[src];
  TGT[(size_t)r * 128 + dw] = val;
}

// ---------------- GRU recurrence + attention (rows independent across B) ----------------
__global__ __launch_bounds__(256)
void gru_attn_k(const float* __restrict__ GI, const uint2* __restrict__ Whp,
                const float* __restrict__ b_ih, const float* __restrict__ b_hh,
                const float* __restrict__ attw, const float* __restrict__ attb,
                float* __restrict__ rep, float* __restrict__ out_attn)
{
  __shared__ float hbuf[2][128];
  __shared__ float red[2][2];
  __shared__ float sc[2][8];
  int tid = threadIdx.x;
  int r = tid >> 7, j = tid & 127;
  int lane = tid & 63, wv = tid >> 6;
  int b = blockIdx.x * 2 + r;
  hbuf[r][j] = 0.f;
  float bi0 = b_ih[j], bi1 = b_ih[128 + j], bi2 = b_ih[256 + j];
  float bh0 = b_hh[j], bh1 = b_hh[128 + j], bh2 = b_hh[256 + j];
  float aw = attw[j], ab = attb[0];
  float ht[8];
  __syncthreads();
  for (int t = 0; t < 8; t++) {
    const float* gi = GI + ((size_t)(t * 1024 + b)) * 384;
    float accr = bh0, accz = bh1, accg = bh2;
#pragma unroll 4
    for (int k = 0; k < 128; k++) {
      float hk = hbuf[r][k];
      uint2 wp = Whp[k * 128 + j];
      accr += hk * bflo(wp.x);
      accz += hk * bfhi(wp.x);
      accg += hk * bflo(wp.y);
    }
    float x0 = gi[j] + bi0, x1 = gi[128 + j] + bi1, x2 = gi[256 + j] + bi2;
    float rg = 1.f / (1.f + __expf(-(x0 + accr)));
    float z  = 1.f / (1.f + __expf(-(x1 + accz)));
    float g  = tanhf(x2 + rg * accg);
    float hp = hbuf[r][j];
    float hn = (1.f - z) * g + z * hp;
    __syncthreads();
    hbuf[r][j] = hn;
    float p = hn * aw;
    for (int off = 32; off; off >>= 1) p += __shfl_down(p, off, 64);
    if (lane == 0) red[wv >> 1][wv & 1] = p;
    __syncthreads();
    if (j == 0) sc[r][t] = tanhf(red[r][0] + red[r][1] + ab);
    ht[t] = hn;
  }
  __syncthreads();
  float s[8], mx = -1e30f;
#pragma unroll
  for (int t = 0; t < 8; t++) { s[t] = sc[r][t]; mx = fmaxf(mx, s[t]); }
  float sum = 0.f;
#pragma unroll
  for (int t = 0; t < 8; t++) { s[t] = __expf(s[t] - mx); sum += s[t]; }
  float inv = 1.f / sum;
  float rv = 0.f;
#pragma unroll
  for (int t = 0; t < 8; t++) rv += s[t] * inv * ht[t];
  rep[(size_t)b * 128 + j] = rv;
  if (j < 8) out_attn[b * 8 + j] = s[j] * inv;
}

// ---------------- final MLP ----------------
__global__ void pred_k(const float* __restrict__ rep, const float* __restrict__ w1,
                       const float* __restrict__ b1, const float* __restrict__ w2,
                       const float* __restrict__ b2, float* __restrict__ out)
{
  int bidx = blockIdx.x * 256 + threadIdx.x;
  if (bidx >= 1024) return;
  const float* rp = rep + (size_t)bidx * 128;
  float acc[16];
#pragma unroll
  for (int i = 0; i < 16; i++) acc[i] = b1[i];
  for (int k = 0; k < 128; k++) {
    float rv = rp[k];
#pragma unroll
    for (int i = 0; i < 16; i++) acc[i] += rv * w1[k * 16 + i];
  }
  float pv = b2[0];
#pragma unroll
  for (int i = 0; i < 16; i++) pv += fmaxf(acc[i], 0.f) * w2[i];
  out[bidx] = pv;
}

extern "C" void kernel_launch(void* const* d_in, const int* in_sizes, int n_in,
                              void* d_out, int out_size, void* d_ws, size_t ws_size,
                              hipStream_t stream)
{
  (void)in_sizes; (void)n_in; (void)out_size; (void)ws_size;
  const float* x      = (const float*)d_in[0];
  const int*   ei     = (const int*)d_in[1];
  const int*   tix    = (const int*)d_in[2];
  const float* proj_w = (const float*)d_in[3];
  const float* proj_b = (const float*)d_in[4];
  const float* gcn_w1 = (const float*)d_in[5];
  const float* gcn_b1 = (const float*)d_in[6];
  const float* gcn_w2 = (const float*)d_in[7];
  const float* gcn_b2 = (const float*)d_in[8];
  const float* w_ih   = (const float*)d_in[9];
  const float* w_hh   = (const float*)d_in[10];
  const float* b_ih   = (const float*)d_in[11];
  const float* b_hh   = (const float*)d_in[12];
  const float* attw   = (const float*)d_in[13];
  const float* attb   = (const float*)d_in[14];
  const float* pw1    = (const float*)d_in[15];
  const float* pb1    = (const float*)d_in[16];
  const float* pw2    = (const float*)d_in[17];
  const float* pb2    = (const float*)d_in[18];
  float* out = (float*)d_out;

  char* ws = (char*)d_ws;
  size_t off = 0;
  auto alloc = [&](size_t bytes) -> char* {
    char* p = ws + off; off += (bytes + 255) & ~(size_t)255; return p;
  };
  int*   counts = (int*)alloc((size_t)NN * 4);
  int*   fill   = (int*)alloc((size_t)NN * 4);
  int*   rp     = (int*)alloc((size_t)(NN + 1) * 4);
  float* dinv   = (float*)alloc((size_t)NN * 4);
  int*   ci     = (int*)alloc((size_t)EE * 4);
  unsigned short* projwt = (unsigned short*)alloc(128 * 256 * 2);
  unsigned short* w1t    = (unsigned short*)alloc(128 * 128 * 2);
  unsigned short* w2t    = (unsigned short*)alloc(128 * 128 * 2);
  unsigned short* wihb   = (unsigned short*)alloc(384 * 256 * 2);
  uint2* whhp            = (uint2*)alloc(128 * 128 * 8);
  unsigned int* TGT = (unsigned int*)alloc((size_t)8192 * 256 * 2);
  float* GI  = (float*)alloc((size_t)8192 * 384 * 4);
  float* rep = (float*)alloc((size_t)1024 * 128 * 4);
  unsigned short* bufA = (unsigned short*)alloc((size_t)ROWS * 128 * 2); // h2
  unsigned short* bufB = (unsigned short*)alloc((size_t)ROWS * 128 * 2); // Ms1, then Ms2
  unsigned short* bufC = (unsigned short*)alloc((size_t)ROWS * 128 * 2); // h1

  const int* e_src = ei;
  const int* e_dst = ei + EE;

  prep_k<<<704, 256, 0, stream>>>(proj_w, gcn_w1, gcn_w2, w_ih, w_hh,
                                  projwt, w1t, w2t, wihb, whhp);
  init_k<<<157, 256, 0, stream>>>(counts, fill);
  count_k<<<2500, 256, 0, stream>>>(e_dst, counts);
  scan_k<<<1, 1024, 0, stream>>>(counts, rp, dinv);
  fill_k<<<2500, 256, 0, stream>>>(e_src, e_dst, rp, fill, ci);

  // fused proj + gcn1 matmul: Ms1 = dinv[row] * (relu(x@Wp+b) @ W1)
  projgcn_k<<<2500, 256, 0, stream>>>(x, (const short*)projwt, (const short*)w1t,
                                      proj_b, dinv, bufB);
  // gcn1 aggregate -> h1
  agg_k<<<80000, 256, 0, stream>>>((const uint2*)bufB, (uint2*)bufC,
                                   rp, ci, dinv, gcn_b1);
  // gcn2 matmul: Ms2 = dinv[row] * (h1 @ w2)
  gemm_k<1><<<dim3(2500, 1), 256, 0, stream>>>(bufC, (const short*)w2t, bufB,
                                               128, 128, dinv);
  // gcn2 aggregate -> h2
  agg_k<<<80000, 256, 0, stream>>>((const uint2*)bufB, (uint2*)bufA,
                                   rp, ci, dinv, gcn_b2);
  // gather targets -> TGT
  gather_k<<<4096, 256, 0, stream>>>((const unsigned int*)bufC, (const unsigned int*)bufA,
                                     tix, TGT);
  // GI = TGT @ w_ih^T  (fp32 out)
  gemm_k<2><<<dim3(64, 3), 256, 0, stream>>>(TGT, (const short*)wihb, GI,
                                             256, 384, nullptr);
  // GRU + attention
  gru_attn_k<<<512, 256, 0, stream>>>(GI, whhp, b_ih, b_hh, attw, attb, rep, out + 1024);
  // prediction MLP
  pred_k<<<4, 256, 0, stream>>>(rep, pw1, pb1, pw2, pb2, out);
}

// Round 3
// 1141.863 us; speedup vs baseline: 1.0265x; 1.0265x over previous
//
#include <hip/hip_runtime.h>
#include <stdint.h>

#define TT 8
#define NN 40000
#define FF 256
#define EE 640000
#define BB 1024
#define ROWS 320000   // TT*NN

typedef __attribute__((ext_vector_type(8))) short s16x8;
typedef __attribute__((ext_vector_type(4))) float f32x4;

__device__ __forceinline__ unsigned short f2bf(float f){
  unsigned int u = __float_as_uint(f);
  u += 0x7fffu + ((u >> 16) & 1u);
  return (unsigned short)(u >> 16);
}
__device__ __forceinline__ float bflo(unsigned int u){ return __uint_as_float(u << 16); }
__device__ __forceinline__ float bfhi(unsigned int u){ return __uint_as_float(u & 0xffff0000u); }

// global -> LDS direct DMA, 16B per lane. LDS dest must be wave-uniform base + lane*16.
// Global source address IS per-lane (enables indexed/indirect staging).
__device__ __forceinline__ void gl2lds16(const void* g, void* l){
  auto gp = reinterpret_cast<const unsigned int __attribute__((address_space(1)))*>(
      reinterpret_cast<uintptr_t>(g));
  auto lp = reinterpret_cast<unsigned int __attribute__((address_space(3)))*>(
      static_cast<unsigned int>(reinterpret_cast<uintptr_t>(l)));
  __builtin_amdgcn_global_load_lds(gp, lp, 16, 0, 0);
}

// ---------------- weight prep (+ CSR counter init) ----------------
__global__ void prep_k(const float* __restrict__ proj_w, const float* __restrict__ w1,
                       const float* __restrict__ w2, const float* __restrict__ wih,
                       const float* __restrict__ whh,
                       unsigned short* __restrict__ projwt, unsigned short* __restrict__ w1t,
                       unsigned short* __restrict__ w2t, unsigned short* __restrict__ wihb,
                       uint2* __restrict__ whhp, int* __restrict__ counts, int* __restrict__ fill)
{
  int i = blockIdx.x * 256 + threadIdx.x;
  if (i < NN) { counts[i] = 0; fill[i] = 0; }
  if (i < 32768) {                      // projwt[p][f] = proj_w[f][p]
    int p = i >> 8, f = i & 255;
    projwt[i] = f2bf(proj_w[f * 128 + p]);
  } else if (i < 49152) {               // w1t[o][c] = w1[c][o]
    int k = i - 32768; int o = k >> 7, c = k & 127;
    w1t[k] = f2bf(w1[c * 128 + o]);
  } else if (i < 65536) {
    int k = i - 49152; int o = k >> 7, c = k & 127;
    w2t[k] = f2bf(w2[c * 128 + o]);
  } else if (i < 163840) {              // wihb = w_ih as-is (rows are output cols)
    int k = i - 65536;
    wihb[k] = f2bf(wih[k]);
  } else if (i < 180224) {              // whhp[k][j] = {whh[j][k], whh[128+j][k], whh[256+j][k], 0}
    int k = i - 163840; int kk = k >> 7, j = k & 127;
    unsigned int lo = (unsigned int)f2bf(whh[j * 128 + kk]) |
                      ((unsigned int)f2bf(whh[(128 + j) * 128 + kk]) << 16);
    unsigned int hi = (unsigned int)f2bf(whh[(256 + j) * 128 + kk]);
    whhp[k] = make_uint2(lo, hi);
  }
}

// ---------------- CSR build ----------------
__global__ void count_k(const int* __restrict__ dst, int* __restrict__ counts){
  int i = blockIdx.x * 256 + threadIdx.x;
  if (i < EE) atomicAdd(&counts[dst[i]], 1);
}
__global__ void scan_k(const int* __restrict__ counts, int* __restrict__ rp,
                       float* __restrict__ dinv)
{
  __shared__ int sums[1024];
  const int CH = 40;
  int t = threadIdx.x;
  int beg = t * CH, end = beg + CH; if (end > NN) end = NN; if (beg > NN) beg = NN;
  int s = 0;
  for (int i = beg; i < end; i++) s += counts[i];
  sums[t] = s;
  __syncthreads();
  for (int off = 1; off < 1024; off <<= 1) {
    int add = (t >= off) ? sums[t - off] : 0;
    __syncthreads();
    sums[t] += add;
    __syncthreads();
  }
  int run = sums[t] - s;   // exclusive prefix for this chunk
  for (int i = beg; i < end; i++) { rp[i] = run; run += counts[i]; }
  if (t == 1023) rp[NN] = sums[1023];
  for (int i = beg; i < end; i++) dinv[i] = rsqrtf((float)(counts[i] + 1));
}
__global__ void fill_k(const int* __restrict__ src, const int* __restrict__ dst,
                       const int* __restrict__ rp, int* __restrict__ fill,
                       int* __restrict__ ci)
{
  int i = blockIdx.x * 256 + threadIdx.x;
  if (i < EE) {
    int d = dst[i];
    int pos = rp[d] + atomicAdd(&fill[d], 1);
    ci[pos] = src[i];
  }
}

// ---------------- tiled MFMA GEMM: C[r][c] = sum_k A[r][k]*Bt[c][k] ----------------
// MODE 1: bf16 out = acc*dinv[row%NN];  MODE 2: f32 out = acc.
// GIA 1: A-rows gathered: row r -> t=r>>10, b=r&1023, node=tix[b];
//        cols 0..127 from Ap(h1) row (t*NN+node), cols 128..255 from A2(h2).
template<int MODE, int GIA>
__global__ __launch_bounds__(256)
void gemm_k(const void* __restrict__ Ap, const short* __restrict__ Bt,
            void* __restrict__ Cp, int K, int ldc,
            const float* __restrict__ dinv,
            const short* __restrict__ A2, const int* __restrict__ tix)
{
  __shared__ short lA[128 * 64];
  __shared__ short lB[128 * 64];
  const int tid = threadIdx.x;
  const int lane = tid & 63, wave = tid >> 6;
  const int row0 = blockIdx.x * 128;
  const int col0 = blockIdx.y * 128;
  const int qr = (wave & 1) * 64, qc = (wave >> 1) * 64;
  const int m = lane & 15, q = lane >> 4;

  f32x4 acc[4][4];
#pragma unroll
  for (int i = 0; i < 4; i++)
#pragma unroll
    for (int j = 0; j < 4; j++) acc[i][j] = (f32x4){0.f, 0.f, 0.f, 0.f};

  for (int k0 = 0; k0 < K; k0 += 64) {
    __syncthreads();
    if (GIA) {
      const short* h1p = (const short*)Ap;
#pragma unroll
      for (int i = 0; i < 4; i++) {
        int c = wave * 4 + i;
        int row = c * 8 + (lane >> 3);
        int kg = (lane & 7) ^ (row & 7);
        int r = row0 + row;
        int tt = r >> 10, bb = r & 1023;
        int node = tix[bb];
        const short* srcp = (k0 < 128) ? h1p : A2;
        gl2lds16(srcp + ((size_t)tt * NN + node) * 128 + (k0 & 127) + kg * 8, lA + c * 512);
      }
    } else {
      const short* A = (const short*)Ap;
#pragma unroll
      for (int i = 0; i < 4; i++) {
        int c = wave * 4 + i;
        int row = c * 8 + (lane >> 3);
        int kg = (lane & 7) ^ (row & 7);
        gl2lds16(A + (size_t)(row0 + row) * K + k0 + kg * 8, lA + c * 512);
      }
    }
#pragma unroll
    for (int i = 0; i < 4; i++) {
      int c = wave * 4 + i;
      int row = c * 8 + (lane >> 3);
      int kg = (lane & 7) ^ (row & 7);
      gl2lds16(Bt + (size_t)(col0 + row) * K + k0 + kg * 8, lB + c * 512);
    }
    __syncthreads();
#pragma unroll
    for (int ks = 0; ks < 2; ks++) {
      s16x8 af[4], bf[4];
#pragma unroll
      for (int i = 0; i < 4; i++) {
        int R = qr + 16 * i + m;
        af[i] = *(const s16x8*)&lA[R * 64 + (((ks * 4 + q) ^ (R & 7)) * 8)];
        int RB = qc + 16 * i + m;
        bf[i] = *(const s16x8*)&lB[RB * 64 + (((ks * 4 + q) ^ (RB & 7)) * 8)];
      }
#pragma unroll
      for (int i = 0; i < 4; i++)
#pragma unroll
        for (int j = 0; j < 4; j++)
          acc[i][j] = __builtin_amdgcn_mfma_f32_16x16x32_bf16(af[i], bf[j], acc[i][j], 0, 0, 0);
    }
  }
#pragma unroll
  for (int i = 0; i < 4; i++) {
    int rbase = row0 + qr + 16 * i + q * 4;
#pragma unroll
    for (int j = 0; j < 4; j++) {
      int col = col0 + qc + 16 * j + m;
#pragma unroll
      for (int rr = 0; rr < 4; rr++) {
        int rg = rbase + rr;
        float v = acc[i][j][rr];
        if (MODE == 1) {
          v *= dinv[rg % NN];
          ((unsigned short*)Cp)[(size_t)rg * ldc + col] = f2bf(v);
        } else {
          ((float*)Cp)[(size_t)rg * ldc + col] = v;
        }
      }
    }
  }
}

// ---------------- fused proj + gcn1 matmul ----------------
// Per 128-row block: Hp = relu(x@Wp + b) kept in LDS (bf16, swizzled), then
// Ms1 = dinv[row] * (Hp @ W1) written directly.
__global__ __launch_bounds__(256)
void projgcn_k(const float* __restrict__ x, const short* __restrict__ projwt,
               const short* __restrict__ w1t, const float* __restrict__ proj_b,
               const float* __restrict__ dinv, unsigned short* __restrict__ Ms1)
{
  __shared__ short lds[128 * 64 * 3];   // 48 KB
  short* lA = lds;                      // 16 KB: x tile (matmul1) / W1 tile (matmul2)
  short* lB = lds + 8192;               // 16 KB: projwt tile (matmul1)
  short* lH = lds + 8192;               // 32 KB: Hp (overwrites lB after matmul1)
  const int tid = threadIdx.x;
  const int lane = tid & 63, wave = tid >> 6;
  const int row0 = blockIdx.x * 128;
  const int qr = (wave & 1) * 64, qc = (wave >> 1) * 64;
  const int m = lane & 15, q = lane >> 4;

  f32x4 acc[4][4];
#pragma unroll
  for (int i = 0; i < 4; i++)
#pragma unroll
    for (int j = 0; j < 4; j++) acc[i][j] = (f32x4){0.f, 0.f, 0.f, 0.f};

  // ---- matmul 1: Hp = x(128x256) @ projwt^T ----
  for (int k0 = 0; k0 < 256; k0 += 64) {
    __syncthreads();
    {   // stage A: fp32 -> bf16
      int row = tid >> 1, half = tid & 1;
      const float* gp = x + (size_t)(row0 + row) * 256 + k0 + half * 32;
#pragma unroll
      for (int gi = 0; gi < 4; gi++) {
        float4 v0 = *(const float4*)(gp + gi * 8);
        float4 v1 = *(const float4*)(gp + gi * 8 + 4);
        uint4 w;
        w.x = (unsigned)f2bf(v0.x) | ((unsigned)f2bf(v0.y) << 16);
        w.y = (unsigned)f2bf(v0.z) | ((unsigned)f2bf(v0.w) << 16);
        w.z = (unsigned)f2bf(v1.x) | ((unsigned)f2bf(v1.y) << 16);
        w.w = (unsigned)f2bf(v1.z) | ((unsigned)f2bf(v1.w) << 16);
        int g = half * 4 + gi;
        *(uint4*)&lA[row * 64 + ((g ^ (row & 7)) * 8)] = w;
      }
    }
#pragma unroll
    for (int i = 0; i < 4; i++) {   // stage B: projwt (K=256)
      int c = wave * 4 + i;
      int row = c * 8 + (lane >> 3);
      int kg = (lane & 7) ^ (row & 7);
      gl2lds16(projwt + (size_t)row * 256 + k0 + kg * 8, lB + c * 512);
    }
    __syncthreads();
#pragma unroll
    for (int ks = 0; ks < 2; ks++) {
      s16x8 af[4], bf[4];
#pragma unroll
      for (int i = 0; i < 4; i++) {
        int R = qr + 16 * i + m;
        af[i] = *(const s16x8*)&lA[R * 64 + (((ks * 4 + q) ^ (R & 7)) * 8)];
        int RB = qc + 16 * i + m;
        bf[i] = *(const s16x8*)&lB[RB * 64 + (((ks * 4 + q) ^ (RB & 7)) * 8)];
      }
#pragma unroll
      for (int i = 0; i < 4; i++)
#pragma unroll
        for (int j = 0; j < 4; j++)
          acc[i][j] = __builtin_amdgcn_mfma_f32_16x16x32_bf16(af[i], bf[j], acc[i][j], 0, 0, 0);
    }
  }
  __syncthreads();   // everyone done reading lA/lB before lH overwrites lB

  // ---- epilogue 1: relu(acc + b) -> lH (bf16, swizzled like an A-tile, k = col) ----
#pragma unroll
  for (int i = 0; i < 4; i++) {
    int rb = qr + 16 * i + q * 4;
#pragma unroll
    for (int j = 0; j < 4; j++) {
      int c = qc + 16 * j + m;
      int chalf = c & 64;
      int gsw = (c >> 3) & 7;
      float bv = proj_b[c];
#pragma unroll
      for (int rr = 0; rr < 4; rr++) {
        int r_loc = rb + rr;
        float v = fmaxf(acc[i][j][rr] + bv, 0.f);
        lH[r_loc * 128 + chalf + ((gsw ^ (r_loc & 7)) << 3) + (c & 7)] = (short)f2bf(v);
      }
      acc[i][j] = (f32x4){0.f, 0.f, 0.f, 0.f};
    }
  }

  // ---- matmul 2: Ms1 = Hp(128x128) @ w1t^T ----
  for (int k0 = 0; k0 < 128; k0 += 64) {
    __syncthreads();
#pragma unroll
    for (int i = 0; i < 4; i++) {   // stage W1 tile into lA (K=128)
      int c = wave * 4 + i;
      int row = c * 8 + (lane >> 3);
      int kg = (lane & 7) ^ (row & 7);
      gl2lds16(w1t + (size_t)row * 128 + k0 + kg * 8, lA + c * 512);
    }
    __syncthreads();
#pragma unroll
    for (int ks = 0; ks < 2; ks++) {
      s16x8 af[4], bf[4];
#pragma unroll
      for (int i = 0; i < 4; i++) {
        int R = qr + 16 * i + m;
        af[i] = *(const s16x8*)&lH[R * 128 + k0 + (((ks * 4 + q) ^ (R & 7)) << 3)];
        int RB = qc + 16 * i + m;
        bf[i] = *(const s16x8*)&lA[RB * 64 + (((ks * 4 + q) ^ (RB & 7)) << 3)];
      }
#pragma unroll
      for (int i = 0; i < 4; i++)
#pragma unroll
        for (int j = 0; j < 4; j++)
          acc[i][j] = __builtin_amdgcn_mfma_f32_16x16x32_bf16(af[i], bf[j], acc[i][j], 0, 0, 0);
    }
  }

  // ---- epilogue 2: Ms1 = dinv[node] * acc ----
#pragma unroll
  for (int i = 0; i < 4; i++) {
    int rbase = row0 + qr + 16 * i + q * 4;
#pragma unroll
    for (int j = 0; j < 4; j++) {
      int col = qc + 16 * j + m;
#pragma unroll
      for (int rr = 0; rr < 4; rr++) {
        int rg = rbase + rr;
        float v = acc[i][j][rr] * dinv[rg % NN];
        Ms1[(size_t)rg * 128 + col] = f2bf(v);
      }
    }
  }
}

// ---------------- GCN aggregation: one wave per (t,node) -------------------
// uint4 loads: 16 lanes x 16 B cover one 256 B row -> 4 edges per wave-load
// (lane group g = lane>>4 handles edge j+g). 16-edge unroll = 16 rows in
// flight. Cross-group combine: 2x shfl_xor at the end. Blocks t-major =>
// ~one 10 MB slab hot at a time.
__global__ __launch_bounds__(256)
void agg_k(const uint4* __restrict__ Ms, uint4* __restrict__ Hout,
           const int* __restrict__ rp, const int* __restrict__ ci,
           const float* __restrict__ dinv, const float* __restrict__ bias)
{
  int widx = blockIdx.x * 4 + (threadIdx.x >> 6);
  int lane = threadIdx.x & 63;
  int li = lane & 15, g = lane >> 4;
  int t = widx / NN;
  int v = widx - t * NN;
  const uint4* base = Ms + (size_t)t * NN * 16 + li;

  float a0 = 0.f, a1 = 0.f, a2 = 0.f, a3 = 0.f, a4 = 0.f, a5 = 0.f, a6 = 0.f, a7 = 0.f;
  if (g == 0) {   // self-loop term
    uint4 su = base[(size_t)v * 16];
    a0 = bflo(su.x); a1 = bfhi(su.x); a2 = bflo(su.y); a3 = bfhi(su.y);
    a4 = bflo(su.z); a5 = bfhi(su.z); a6 = bflo(su.w); a7 = bfhi(su.w);
  }

  int e0 = rp[v], e1 = rp[v + 1];
  for (int chunk = e0; chunk < e1; chunk += 64) {
    int cnt = min(64, e1 - chunk);
    int myIdx = (lane < cnt) ? ci[chunk + lane] : 0;
    int j = 0;
    for (; j + 16 <= cnt; j += 16) {
      int s0 = __shfl(myIdx, j + g, 64);
      int s1 = __shfl(myIdx, j + 4 + g, 64);
      int s2 = __shfl(myIdx, j + 8 + g, 64);
      int s3 = __shfl(myIdx, j + 12 + g, 64);
      uint4 w0 = base[(size_t)s0 * 16];
      uint4 w1 = base[(size_t)s1 * 16];
      uint4 w2 = base[(size_t)s2 * 16];
      uint4 w3 = base[(size_t)s3 * 16];
      a0 += bflo(w0.x) + bflo(w1.x) + bflo(w2.x) + bflo(w3.x);
      a1 += bfhi(w0.x) + bfhi(w1.x) + bfhi(w2.x) + bfhi(w3.x);
      a2 += bflo(w0.y) + bflo(w1.y) + bflo(w2.y) + bflo(w3.y);
      a3 += bfhi(w0.y) + bfhi(w1.y) + bfhi(w2.y) + bfhi(w3.y);
      a4 += bflo(w0.z) + bflo(w1.z) + bflo(w2.z) + bflo(w3.z);
      a5 += bfhi(w0.z) + bfhi(w1.z) + bfhi(w2.z) + bfhi(w3.z);
      a6 += bflo(w0.w) + bflo(w1.w) + bflo(w2.w) + bflo(w3.w);
      a7 += bfhi(w0.w) + bfhi(w1.w) + bfhi(w2.w) + bfhi(w3.w);
    }
    for (; j + 4 <= cnt; j += 4) {
      int s = __shfl(myIdx, j + g, 64);
      uint4 w = base[(size_t)s * 16];
      a0 += bflo(w.x); a1 += bfhi(w.x); a2 += bflo(w.y); a3 += bfhi(w.y);
      a4 += bflo(w.z); a5 += bfhi(w.z); a6 += bflo(w.w); a7 += bfhi(w.w);
    }
    int rem = cnt - j;
    if (rem > 0) {
      int sidx = j + g; if (sidx >= cnt) sidx = j;   // keep shfl src in-range
      int s = __shfl(myIdx, sidx, 64);
      if (g < rem) {
        uint4 w = base[(size_t)s * 16];
        a0 += bflo(w.x); a1 += bfhi(w.x); a2 += bflo(w.y); a3 += bfhi(w.y);
        a4 += bflo(w.z); a5 += bfhi(w.z); a6 += bflo(w.w); a7 += bfhi(w.w);
      }
    }
  }
  a0 += __shfl_xor(a0, 16, 64); a0 += __shfl_xor(a0, 32, 64);
  a1 += __shfl_xor(a1, 16, 64); a1 += __shfl_xor(a1, 32, 64);
  a2 += __shfl_xor(a2, 16, 64); a2 += __shfl_xor(a2, 32, 64);
  a3 += __shfl_xor(a3, 16, 64); a3 += __shfl_xor(a3, 32, 64);
  a4 += __shfl_xor(a4, 16, 64); a4 += __shfl_xor(a4, 32, 64);
  a5 += __shfl_xor(a5, 16, 64); a5 += __shfl_xor(a5, 32, 64);
  a6 += __shfl_xor(a6, 16, 64); a6 += __shfl_xor(a6, 32, 64);
  a7 += __shfl_xor(a7, 16, 64); a7 += __shfl_xor(a7, 32, 64);
  if (g == 0) {
    float dv = dinv[v];
    float r0 = fmaxf(fmaf(dv, a0, bias[li * 8 + 0]), 0.f);
    float r1 = fmaxf(fmaf(dv, a1, bias[li * 8 + 1]), 0.f);
    float r2 = fmaxf(fmaf(dv, a2, bias[li * 8 + 2]), 0.f);
    float r3 = fmaxf(fmaf(dv, a3, bias[li * 8 + 3]), 0.f);
    float r4 = fmaxf(fmaf(dv, a4, bias[li * 8 + 4]), 0.f);
    float r5 = fmaxf(fmaf(dv, a5, bias[li * 8 + 5]), 0.f);
    float r6 = fmaxf(fmaf(dv, a6, bias[li * 8 + 6]), 0.f);
    float r7 = fmaxf(fmaf(dv, a7, bias[li * 8 + 7]), 0.f);
    uint4 o;
    o.x = (unsigned)f2bf(r0) | ((unsigned)f2bf(r1) << 16);
    o.y = (unsigned)f2bf(r2) | ((unsigned)f2bf(r3) << 16);
    o.z = (unsigned)f2bf(r4) | ((unsigned)f2bf(r5) << 16);
    o.w = (unsigned)f2bf(r6) | ((unsigned)f2bf(r7) << 16);
    Hout[(size_t)widx * 16 + li] = o;
  }
}

// ---------------- GRU recurrence + attention + prediction MLP ----------------
__global__ __launch_bounds__(256)
void gru_attn_k(const float* __restrict__ GI, const uint2* __restrict__ Whp,
                const float* __restrict__ b_ih, const float* __restrict__ b_hh,
                const float* __restrict__ attw, const float* __restrict__ attb,
                const float* __restrict__ pw1, const float* __restrict__ pb1,
                const float* __restrict__ pw2, const float* __restrict__ pb2,
                float* __restrict__ out)   // out[0..1023]=pred, out[1024..]=attn
{
  __shared__ float hbuf[2][128];
  __shared__ float red[2][2];
  __shared__ float sc[2][8];
  int tid = threadIdx.x;
  int r = tid >> 7, j = tid & 127;
  int lane = tid & 63, wv = tid >> 6;
  int b = blockIdx.x * 2 + r;
  hbuf[r][j] = 0.f;
  float bi0 = b_ih[j], bi1 = b_ih[128 + j], bi2 = b_ih[256 + j];
  float bh0 = b_hh[j], bh1 = b_hh[128 + j], bh2 = b_hh[256 + j];
  float aw = attw[j], ab = attb[0];
  float ht[8];
  __syncthreads();
  for (int t = 0; t < 8; t++) {
    const float* gi = GI + ((size_t)(t * 1024 + b)) * 384;
    float accr = bh0, accz = bh1, accg = bh2;
#pragma unroll 4
    for (int k = 0; k < 128; k++) {
      float hk = hbuf[r][k];
      uint2 wp = Whp[k * 128 + j];
      accr += hk * bflo(wp.x);
      accz += hk * bfhi(wp.x);
      accg += hk * bflo(wp.y);
    }
    float x0 = gi[j] + bi0, x1 = gi[128 + j] + bi1, x2 = gi[256 + j] + bi2;
    float rg = 1.f / (1.f + __expf(-(x0 + accr)));
    float z  = 1.f / (1.f + __expf(-(x1 + accz)));
    float g  = tanhf(x2 + rg * accg);
    float hp = hbuf[r][j];
    float hn = (1.f - z) * g + z * hp;
    __syncthreads();
    hbuf[r][j] = hn;
    float p = hn * aw;
    for (int off = 32; off; off >>= 1) p += __shfl_down(p, off, 64);
    if (lane == 0) red[wv >> 1][wv & 1] = p;
    __syncthreads();
    if (j == 0) sc[r][t] = tanhf(red[r][0] + red[r][1] + ab);
    ht[t] = hn;
  }
  __syncthreads();
  float s[8], mx = -1e30f;
#pragma unroll
  for (int t = 0; t < 8; t++) { s[t] = sc[r][t]; mx = fmaxf(mx, s[t]); }
  float sum = 0.f;
#pragma unroll
  for (int t = 0; t < 8; t++) { s[t] = __expf(s[t] - mx); sum += s[t]; }
  float inv = 1.f / sum;
  float rv = 0.f;
#pragma unroll
  for (int t = 0; t < 8; t++) rv += s[t] * inv * ht[t];
  if (j < 8) out[1024 + b * 8 + j] = s[j] * inv;
  hbuf[r][j] = rv;               // rep row staged in LDS for the fused MLP
  __syncthreads();
  if (j < 16) {
    float acc = pb1[j];
#pragma unroll 4
    for (int k = 0; k < 128; k++) acc += hbuf[r][k] * pw1[k * 16 + j];
    float p = fmaxf(acc, 0.f) * pw2[j];
    p += __shfl_down(p, 8, 64);
    p += __shfl_down(p, 4, 64);
    p += __shfl_down(p, 2, 64);
    p += __shfl_down(p, 1, 64);
    if (j == 0) out[b] = p + pb2[0];
  }
}

extern "C" void kernel_launch(void* const* d_in, const int* in_sizes, int n_in,
                              void* d_out, int out_size, void* d_ws, size_t ws_size,
                              hipStream_t stream)
{
  (void)in_sizes; (void)n_in; (void)out_size; (void)ws_size;
  const float* x      = (const float*)d_in[0];
  const int*   ei     = (const int*)d_in[1];
  const int*   tix    = (const int*)d_in[2];
  const float* proj_w = (const float*)d_in[3];
  const float* proj_b = (const float*)d_in[4];
  const float* gcn_w1 = (const float*)d_in[5];
  const float* gcn_b1 = (const float*)d_in[6];
  const float* gcn_w2 = (const float*)d_in[7];
  const float* gcn_b2 = (const float*)d_in[8];
  const float* w_ih   = (const float*)d_in[9];
  const float* w_hh   = (const float*)d_in[10];
  const float* b_ih   = (const float*)d_in[11];
  const float* b_hh   = (const float*)d_in[12];
  const float* attw   = (const float*)d_in[13];
  const float* attb   = (const float*)d_in[14];
  const float* pw1    = (const float*)d_in[15];
  const float* pb1    = (const float*)d_in[16];
  const float* pw2    = (const float*)d_in[17];
  const float* pb2    = (const float*)d_in[18];
  float* out = (float*)d_out;

  char* ws = (char*)d_ws;
  size_t off = 0;
  auto alloc = [&](size_t bytes) -> char* {
    char* p = ws + off; off += (bytes + 255) & ~(size_t)255; return p;
  };
  int*   counts = (int*)alloc((size_t)NN * 4);
  int*   fill   = (int*)alloc((size_t)NN * 4);
  int*   rp     = (int*)alloc((size_t)(NN + 1) * 4);
  float* dinv   = (float*)alloc((size_t)NN * 4);
  int*   ci     = (int*)alloc((size_t)EE * 4);
  unsigned short* projwt = (unsigned short*)alloc(128 * 256 * 2);
  unsigned short* w1t    = (unsigned short*)alloc(128 * 128 * 2);
  unsigned short* w2t    = (unsigned short*)alloc(128 * 128 * 2);
  unsigned short* wihb   = (unsigned short*)alloc(384 * 256 * 2);
  uint2* whhp            = (uint2*)alloc(128 * 128 * 8);
  float* GI  = (float*)alloc((size_t)8192 * 384 * 4);
  unsigned short* bufA = (unsigned short*)alloc((size_t)ROWS * 128 * 2); // h2
  unsigned short* bufB = (unsigned short*)alloc((size_t)ROWS * 128 * 2); // Ms1, then Ms2
  unsigned short* bufC = (unsigned short*)alloc((size_t)ROWS * 128 * 2); // h1

  const int* e_src = ei;
  const int* e_dst = ei + EE;

  prep_k<<<704, 256, 0, stream>>>(proj_w, gcn_w1, gcn_w2, w_ih, w_hh,
                                  projwt, w1t, w2t, wihb, whhp, counts, fill);
  count_k<<<2500, 256, 0, stream>>>(e_dst, counts);
  scan_k<<<1, 1024, 0, stream>>>(counts, rp, dinv);
  fill_k<<<2500, 256, 0, stream>>>(e_src, e_dst, rp, fill, ci);

  // fused proj + gcn1 matmul: Ms1 = dinv[row] * (relu(x@Wp+b) @ W1)
  projgcn_k<<<2500, 256, 0, stream>>>(x, (const short*)projwt, (const short*)w1t,
                                      proj_b, dinv, bufB);
  // gcn1 aggregate -> h1
  agg_k<<<80000, 256, 0, stream>>>((const uint4*)bufB, (uint4*)bufC,
                                   rp, ci, dinv, gcn_b1);
  // gcn2 matmul: Ms2 = dinv[row] * (h1 @ w2)
  gemm_k<1, 0><<<dim3(2500, 1), 256, 0, stream>>>(bufC, (const short*)w2t, bufB,
                                                  128, 128, dinv, nullptr, nullptr);
  // gcn2 aggregate -> h2
  agg_k<<<80000, 256, 0, stream>>>((const uint4*)bufB, (uint4*)bufA,
                                   rp, ci, dinv, gcn_b2);
  // GI = TGT @ w_ih^T with A-rows gathered straight from h1/h2 via tix
  gemm_k<2, 1><<<dim3(64, 3), 256, 0, stream>>>(bufC, (const short*)wihb, GI,
                                                256, 384, nullptr,
                                                (const short*)bufA, (const int*)tix);
  // GRU + attention + prediction MLP
  gru_attn_k<<<512, 256, 0, stream>>>(GI, whhp, b_ih, b_hh, attw, attb,
                                      pw1, pb1, pw2, pb2, out);
}